// Round 2
// baseline (230.055 us; speedup 1.0000x reference)
//
#include <hip/hip_runtime.h>
#include <math.h>

#define N_ROWS 400      // bs*Q
#define M_ROWS 80       // = 5*16
#define K_CLS  134
#define PN     12544
#define PFULL  65536    // 256*256
#define WORDS  (PFULL / 32)   // 2048 bitmap words == full-grid t-steps
#define NSUB   25       // 400/16 n-subtiles
#define KS     32       // k-chunks (full-grid split)
#define TCH    (WORDS / KS)   // 64 t-steps per chunk = 2048 positions
#define NM     (N_ROWS * M_ROWS)

typedef __attribute__((ext_vector_type(4))) float  f32x4;
typedef __attribute__((ext_vector_type(8))) __bf16 bf16x8;

__device__ __forceinline__ float wave_reduce_sum(float v) {
#pragma unroll
    for (int off = 32; off > 0; off >>= 1) v += __shfl_down(v, off, 64);
    return v;
}

// --- block 0: build selection bitmap (no rank scan needed anymore).
//     blocks 1..25: softmax stats (16 rows each, one per wave). ---
__global__ __launch_bounds__(1024) void sort_softmax_kernel(
        const int* __restrict__ point_idx,
        unsigned int* __restrict__ bitmap_g,
        const float* __restrict__ pred_logits,
        float* __restrict__ rowmax, float* __restrict__ rowsum) {
    int tid = threadIdx.x;
    if (blockIdx.x == 0) {
        __shared__ unsigned int bits[WORDS];   // 8 KB
        bits[tid] = 0u; bits[tid + 1024] = 0u;
        __syncthreads();
        for (int i = tid; i < PN; i += 1024) {
            int p = point_idx[i];
            atomicOr(&bits[p >> 5], 1u << (p & 31));
        }
        __syncthreads();
        bitmap_g[tid]        = bits[tid];
        bitmap_g[tid + 1024] = bits[tid + 1024];
    } else {
        int wave = tid >> 6, lane = tid & 63;
        int n = (blockIdx.x - 1) * 16 + wave;       // < 400
        const float* row = pred_logits + n * K_CLS;
        float mx = -1e30f;
        for (int k = lane; k < K_CLS; k += 64) mx = fmaxf(mx, row[k]);
#pragma unroll
        for (int off = 32; off > 0; off >>= 1) mx = fmaxf(mx, __shfl_down(mx, off, 64));
        mx = __shfl(mx, 0, 64);
        float se = 0.f;
        for (int k = lane; k < K_CLS; k += 64) se += expf(row[k] - mx);
        se = wave_reduce_sum(se);
        if (lane == 0) { rowmax[n] = mx; rowsum[n] = se; }
    }
}

// --- build Y' bit matrix: yb[m][w] = pack(y>0.5) & sel_bits, plus ysum
//     partials via popc. Reads tgt_masks fully coalesced. ---
__global__ __launch_bounds__(256) void buildY_kernel(
        const float* __restrict__ tgt_masks,
        const unsigned int* __restrict__ bitmap_g,
        unsigned int* __restrict__ yb_g, float* __restrict__ ypart) {
    __shared__ float smem[4];
    int b = blockIdx.x;
    int m = b >> 3, ch = b & 7;            // 8 chunks of 8192 positions
    int wave = threadIdx.x >> 6, lane = threadIdx.x & 63;
    const float* row = tgt_masks + (size_t)m * PFULL + ch * 8192 + wave * 2048;
    unsigned int* dst = yb_g + (size_t)m * WORDS + ch * 256 + wave * 64;
    const unsigned int* selw = bitmap_g + ch * 256 + wave * 64;
    int cnt = 0;
    for (int it = 0; it < 32; ++it) {
        float v = row[it * 64 + lane];
        unsigned long long bal = __ballot(v > 0.5f);
        unsigned int lo = (unsigned int)bal & selw[it * 2];
        unsigned int hi = (unsigned int)(bal >> 32) & selw[it * 2 + 1];
        if (lane == 0) { dst[it * 2] = lo; cnt += __popc(lo) + __popc(hi); }
        if (lane == 1) dst[it * 2 + 1] = hi;
    }
    if (lane == 0) smem[wave] = (float)cnt;
    __syncthreads();
    if (threadIdx.x == 0)
        ypart[ch * M_ROWS + m] = smem[0] + smem[1] + smem[2] + smem[3];
}

// --- full-grid fused GEMM: A = pred_masks streamed coalesced (read ONCE),
//     B = binary Y' expanded from bits via 4-bit LDS LUT. Zero-positions
//     contribute exactly 0 to the f32 accumulators, so results match the
//     compacted GEMM bit-for-bit on xy/sy. rowS/rowSP via bitmap-predicated
//     f32 adds. Partials per k-chunk, zero global atomics. ---
__global__ __launch_bounds__(256) void gemm_full_kernel(
        const float* __restrict__ pred_masks,
        const unsigned int* __restrict__ bitmap_g,
        const unsigned int* __restrict__ yb_g,
        float* __restrict__ xypart, float* __restrict__ sypart,
        float* __restrict__ rowS, float* __restrict__ rowSP) {
    __shared__ float red[4][40][64];       // 40 KB (aliased as ybl/sell in phase 1)
    __shared__ float rowred[4][2][16];
    __shared__ __align__(8) unsigned int lut[32];   // 16 nibbles -> 4 bf16 (2 u32)
    unsigned int* ybl  = (unsigned int*)red;             // [tl][80] -> 20480 B
    unsigned int* sell = ((unsigned int*)red) + TCH * 80;  // 64 words

    int tid = threadIdx.x;
    int wave = tid >> 6, lane = tid & 63;
    int colL = lane & 15, quad = lane >> 4;
    int nsub = blockIdx.x / KS, ch = blockIdx.x % KS;
    int n0 = nsub * 16;
    int t0 = ch * TCH;                     // word index == t-step index

    if (tid < 16) {
        unsigned int lo = ((tid & 1) ? 0x3F80u : 0u) | ((tid & 2) ? 0x3F800000u : 0u);
        unsigned int hi = ((tid & 4) ? 0x3F80u : 0u) | ((tid & 8) ? 0x3F800000u : 0u);
        lut[tid * 2] = lo; lut[tid * 2 + 1] = hi;
    }
    // stage Y' bit-words transposed [tl][m] (conflict-free reads) + sel words
    for (int i = tid; i < M_ROWS * TCH; i += 256) {
        int m = i >> 6, tl = i & 63;
        ybl[tl * 80 + m] = yb_g[(size_t)m * WORDS + t0 + tl];
    }
    for (int i = tid; i < TCH; i += 256) sell[i] = bitmap_g[t0 + i];
    __syncthreads();

    const float* rowp = pred_masks + (size_t)(n0 + colL) * PFULL;
    const uint2* lutp = (const uint2*)lut;

    f32x4 accX[5], accS[5];
    f32x4 zero = {0.f, 0.f, 0.f, 0.f};
#pragma unroll
    for (int j = 0; j < 5; ++j) { accX[j] = zero; accS[j] = zero; }
    float sumS = 0.f, sumSP = 0.f;

    int tl0 = wave * 16;                   // each wave owns 16 contiguous t-steps
    int kbase = (t0 + tl0) * 32 + quad * 8;
    f32x4 pa = *(const f32x4*)(rowp + kbase);
    f32x4 pb = *(const f32x4*)(rowp + kbase + 4);

#pragma unroll 4
    for (int i = 0; i < 16; ++i) {
        int tl = tl0 + i;
        f32x4 xa = pa, xb = pb;
        if (i < 15) {
            int kn = kbase + (i + 1) * 32;
            pa = *(const f32x4*)(rowp + kn);
            pb = *(const f32x4*)(rowp + kn + 4);
        }
        unsigned int mb = (sell[tl] >> (quad * 8)) & 0xFFu;
        float xsv[8];
        *(f32x4*)(xsv) = xa; *(f32x4*)(xsv + 4) = xb;
        bf16x8 aX, aS;
#pragma unroll
        for (int jj = 0; jj < 8; ++jj) {
            float x  = xsv[jj];
            float ax = fabsf(x);
            float e  = __expf(-ax);
            float inv = __builtin_amdgcn_rcpf(1.f + e);
            float sig = (x >= 0.f) ? inv : e * inv;
            float sp  = fmaxf(x, 0.f) + __logf(1.f + e);
            aX[jj] = (__bf16)x; aS[jj] = (__bf16)sig;
            if (mb & (1u << jj)) { sumS += sig; sumSP += sp; }
        }
#pragma unroll
        for (int j = 0; j < 5; ++j) {
            unsigned int w  = ybl[tl * 80 + 16 * j + colL];
            unsigned int by = (w >> (quad * 8)) & 0xFFu;
            union { bf16x8 v; uint2 u[2]; } Bb;
            Bb.u[0] = lutp[by & 15u];
            Bb.u[1] = lutp[by >> 4];
            accX[j] = __builtin_amdgcn_mfma_f32_16x16x32_bf16(aX, Bb.v, accX[j], 0, 0, 0);
            accS[j] = __builtin_amdgcn_mfma_f32_16x16x32_bf16(aS, Bb.v, accS[j], 0, 0, 0);
        }
    }

    __syncthreads();   // all waves done reading ybl (aliases red)
    // ---- stash accumulators in LDS ----
#pragma unroll
    for (int j = 0; j < 5; ++j)
#pragma unroll
        for (int r = 0; r < 4; ++r) {
            red[wave][j * 4 + r][lane]      = accX[j][r];
            red[wave][20 + j * 4 + r][lane] = accS[j][r];
        }
    sumS  += __shfl_down(sumS, 32, 64);
    sumS  += __shfl_down(sumS, 16, 64);
    sumSP += __shfl_down(sumSP, 32, 64);
    sumSP += __shfl_down(sumSP, 16, 64);
    if (lane < 16) { rowred[wave][0][lane] = sumS; rowred[wave][1][lane] = sumSP; }
    __syncthreads();
    // ---- each wave reduces a 10-value slice across the 4 waves ----
#pragma unroll
    for (int v0 = 0; v0 < 10; ++v0) {
        int v = wave * 10 + v0;
        float s = red[0][v][lane] + red[1][v][lane] + red[2][v][lane] + red[3][v][lane];
        int vv = (v < 20) ? v : v - 20;
        int j = vv >> 2, r = vv & 3;
        int n = n0 + quad * 4 + r, m = 16 * j + colL;   // verified C/D layout
        float* dst = (v < 20) ? xypart : sypart;
        dst[(size_t)ch * NM + n * M_ROWS + m] = s;
    }
    if (tid < 16) {
        rowS[ch * N_ROWS + n0 + tid] =
            rowred[0][0][tid] + rowred[1][0][tid] +
            rowred[2][0][tid] + rowred[3][0][tid];
    } else if (tid < 32) {
        int l = tid - 16;
        rowSP[ch * N_ROWS + n0 + l] =
            rowred[0][1][l] + rowred[1][1][l] +
            rowred[2][1][l] + rowred[3][1][l];
    }
}

// --- combine: reduce partials (32 k-chunks, 8 y-chunks) + all cost terms ---
__global__ void combine_kernel(const float* __restrict__ logits,
                               const int* __restrict__ tgt_labels,
                               const float* __restrict__ rowmax,
                               const float* __restrict__ rowsum,
                               const float* __restrict__ rowS,
                               const float* __restrict__ rowSP,
                               const float* __restrict__ ypart,
                               const float* __restrict__ xypart,
                               const float* __restrict__ sypart,
                               float* __restrict__ out) {
    int idx = blockIdx.x * blockDim.x + threadIdx.x;
    if (idx >= NM) return;
    int n = idx / M_ROWS, m = idx % M_ROWS;
    float xy = 0.f, sy = 0.f, ssumv = 0.f, spsumv = 0.f, ysum = 0.f;
#pragma unroll 8
    for (int g = 0; g < KS; ++g) {
        xy += xypart[(size_t)g * NM + idx];
        sy += sypart[(size_t)g * NM + idx];
        ssumv  += rowS[g * N_ROWS + n];
        spsumv += rowSP[g * N_ROWS + n];
    }
#pragma unroll
    for (int g = 0; g < 8; ++g) ysum += ypart[g * M_ROWS + m];
    int tid = tgt_labels[m];
    tid = min(max(tid, 0), K_CLS - 1);
    float p = expf(logits[n * K_CLS + tid] - rowmax[n]) / rowsum[n];
    float cost_class = -p;
    float cost_mask = (spsumv - xy) * (1.0f / PN);
    float cost_dice = 1.f - (2.f * sy + 1.f) / (ssumv + ysum + 1.f);
    out[idx] = 2.f * cost_class + 5.f * cost_mask + 5.f * cost_dice;
}

extern "C" void kernel_launch(void* const* d_in, const int* in_sizes, int n_in,
                              void* d_out, int out_size, void* d_ws, size_t ws_size,
                              hipStream_t stream) {
    const float* pred_logits = (const float*)d_in[0];   // (4,100,134)
    const float* pred_masks  = (const float*)d_in[1];   // (4,100,256,256)
    const int*   tgt_labels  = (const int*)d_in[2];     // (80,)
    const float* tgt_masks   = (const float*)d_in[3];   // (80,256,256)
    const int*   point_idx   = (const int*)d_in[4];     // (12544,)
    float* out = (float*)d_out;                         // (4,100,80)

    char* ws = (char*)d_ws;
    size_t off = 0;
    auto carve = [&](size_t nbytes) {
        char* p = ws + off;
        off += (nbytes + 255) & ~(size_t)255;
        return p;
    };
    // all buffers fully overwritten every launch -> NO zero-init anywhere
    unsigned int* bitmap = (unsigned int*)carve(WORDS * 4);            // 8 KB
    unsigned int* yb     = (unsigned int*)carve((size_t)M_ROWS * WORDS * 4); // 640 KB
    float* rowmax = (float*)carve(N_ROWS * 4);
    float* rowsum = (float*)carve(N_ROWS * 4);
    float* ypart  = (float*)carve(8 * M_ROWS * 4);
    float* rowS   = (float*)carve(KS * N_ROWS * 4);
    float* rowSP  = (float*)carve(KS * N_ROWS * 4);
    float* xypart = (float*)carve((size_t)KS * NM * 4);                // 4.1 MB
    float* sypart = (float*)carve((size_t)KS * NM * 4);                // 4.1 MB
    (void)ws_size; (void)in_sizes; (void)n_in; (void)out_size;

    sort_softmax_kernel<<<26, 1024, 0, stream>>>(point_idx, bitmap,
                                                 pred_logits, rowmax, rowsum);
    buildY_kernel<<<M_ROWS * 8, 256, 0, stream>>>(tgt_masks, bitmap, yb, ypart);
    gemm_full_kernel<<<NSUB * KS, 256, 0, stream>>>(
        pred_masks, bitmap, yb, xypart, sypart, rowS, rowSP);
    combine_kernel<<<(NM + 255) / 256, 256, 0, stream>>>(
        pred_logits, tgt_labels, rowmax, rowsum, rowS, rowSP, ypart,
        xypart, sypart, out);
}

// Round 3
// 222.184 us; speedup vs baseline: 1.0354x; 1.0354x over previous
//
#include <hip/hip_runtime.h>
#include <math.h>

#define N_ROWS 400      // bs*Q
#define M_ROWS 80       // = 5*16
#define K_CLS  134
#define PN     12544
#define PFULL  65536    // 256*256
#define WORDS  (PFULL / 32)   // 2048 bitmap words == full-grid t-steps
#define NSUB   25       // 400/16 n-subtiles
#define KS     32       // k-chunks (full-grid split)
#define TCH    (WORDS / KS)   // 64 t-steps per chunk
#define NM     (N_ROWS * M_ROWS)
#define YTCH   256      // buildY t-chunks (8 t each)

typedef __attribute__((ext_vector_type(4))) float  f32x4;
typedef __attribute__((ext_vector_type(8))) __bf16 bf16x8;

__device__ __forceinline__ float wave_reduce_sum(float v) {
#pragma unroll
    for (int off = 32; off > 0; off >>= 1) v += __shfl_down(v, off, 64);
    return v;
}

// --- block 0: build selection bitmap. blocks 1..25: softmax stats. ---
__global__ __launch_bounds__(1024) void sort_softmax_kernel(
        const int* __restrict__ point_idx,
        unsigned int* __restrict__ bitmap_g,
        const float* __restrict__ pred_logits,
        float* __restrict__ rowmax, float* __restrict__ rowsum) {
    int tid = threadIdx.x;
    if (blockIdx.x == 0) {
        __shared__ unsigned int bits[WORDS];   // 8 KB
        bits[tid] = 0u; bits[tid + 1024] = 0u;
        __syncthreads();
        for (int i = tid; i < PN; i += 1024) {
            int p = point_idx[i];
            atomicOr(&bits[p >> 5], 1u << (p & 31));
        }
        __syncthreads();
        bitmap_g[tid]        = bits[tid];
        bitmap_g[tid + 1024] = bits[tid + 1024];
    } else {
        int wave = tid >> 6, lane = tid & 63;
        int n = (blockIdx.x - 1) * 16 + wave;       // < 400
        const float* row = pred_logits + n * K_CLS;
        float mx = -1e30f;
        for (int k = lane; k < K_CLS; k += 64) mx = fmaxf(mx, row[k]);
#pragma unroll
        for (int off = 32; off > 0; off >>= 1) mx = fmaxf(mx, __shfl_down(mx, off, 64));
        mx = __shfl(mx, 0, 64);
        float se = 0.f;
        for (int k = lane; k < K_CLS; k += 64) se += expf(row[k] - mx);
        se = wave_reduce_sum(se);
        if (lane == 0) { rowmax[n] = mx; rowsum[n] = se; }
    }
}

// --- build Y' directly as bf16 MFMA B-fragments, plus sel-fragment (slot 5)
//     and ypart partials. Frag (t,j): lane l holds B[k=t*32+(l>>4)*8+jj][m=16j+(l&15)].
//     Slot 5 column 0 = sel bits (enables MFMA row-sums in the GEMM). ---
__global__ __launch_bounds__(512) void buildY_kernel(
        const float* __restrict__ tgt_masks,
        const unsigned int* __restrict__ bitmap_g,
        bf16x8* __restrict__ Yb, float* __restrict__ ypart) {
    __shared__ float smem[128];
    int b = blockIdx.x;
    int j = b >> 8, tch = b & 255;
    int wave = threadIdx.x >> 6, lane = threadIdx.x & 63;
    int colL = lane & 15, quad = lane >> 4;
    int t = tch * 8 + wave;
    unsigned int w = bitmap_g[t];
    bf16x8 v;
    if (j < 5) {
        int m = 16 * j + colL;
        const float* yrow = tgt_masks + (size_t)m * PFULL + t * 32 + quad * 8;
        f32x4 ya = *(const f32x4*)(yrow);
        f32x4 yc = *(const f32x4*)(yrow + 4);
        float acc = 0.f;
#pragma unroll
        for (int jj = 0; jj < 4; ++jj) {
            float va = ((w >> (quad * 8 + jj)) & 1u)     ? (ya[jj] > 0.5f ? 1.f : 0.f) : 0.f;
            float vc = ((w >> (quad * 8 + jj + 4)) & 1u) ? (yc[jj] > 0.5f ? 1.f : 0.f) : 0.f;
            v[jj] = (__bf16)va; v[jj + 4] = (__bf16)vc;
            acc += va + vc;
        }
        Yb[((size_t)t * 6 + j) * 64 + lane] = v;
        acc += __shfl_down(acc, 32, 64);
        acc += __shfl_down(acc, 16, 64);
        if (quad == 0) smem[wave * 16 + colL] = acc;
        __syncthreads();
        if (threadIdx.x < 16) {
            float s = 0.f;
#pragma unroll
            for (int wv = 0; wv < 8; ++wv) s += smem[wv * 16 + threadIdx.x];
            ypart[tch * M_ROWS + 16 * j + threadIdx.x] = s;
        }
    } else {
        // sel fragment: column 0 only
#pragma unroll
        for (int jj = 0; jj < 8; ++jj) {
            float sv = (colL == 0 && ((w >> (quad * 8 + jj)) & 1u)) ? 1.f : 0.f;
            v[jj] = (__bf16)sv;
        }
        Yb[((size_t)t * 6 + 5) * 64 + lane] = v;
    }
}

// --- full-grid fused GEMM. Inner loop: {A f32x4 loads (HBM, 2-ahead),
//     6 B-fragment loads (L2), sigmoid/softplus math, 12 MFMA}. No LDS,
//     no predication: masked row-sums come from the sel fragment (slot 5).
//     Epilogue: two-pass LDS reduce (20.75 KB total -> 7 blocks/CU). ---
__global__ __launch_bounds__(256) void gemm_full_kernel(
        const float* __restrict__ pred_masks,
        const bf16x8* __restrict__ Yb,
        float* __restrict__ xypart, float* __restrict__ sypart,
        float* __restrict__ rowS, float* __restrict__ rowSP) {
    __shared__ float red[4][20][64];       // 20 KB
    __shared__ float rS[4][16], rSP[4][16];
    int tid = threadIdx.x;
    int wave = tid >> 6, lane = tid & 63;
    int colL = lane & 15, quad = lane >> 4;
    int nsub = blockIdx.x % NSUB, ch = blockIdx.x / NSUB;  // nsub fastest: 25
    int n0 = nsub * 16;                                    // consecutive blocks
    int t0 = ch * TCH + wave * 16;                         // share the Yb slice
    const float* rowp = pred_masks + (size_t)(n0 + colL) * PFULL;
    int kbase = t0 * 32 + quad * 8;

    f32x4 accX[5], accS[5];
    f32x4 zero = {0.f, 0.f, 0.f, 0.f};
#pragma unroll
    for (int j = 0; j < 5; ++j) { accX[j] = zero; accS[j] = zero; }
    f32x4 acc5S = zero, acc5P = zero;

    // A prefetch, 2 iterations ahead
    f32x4 pa0 = *(const f32x4*)(rowp + kbase);
    f32x4 pb0 = *(const f32x4*)(rowp + kbase + 4);
    f32x4 pa1 = *(const f32x4*)(rowp + kbase + 32);
    f32x4 pb1 = *(const f32x4*)(rowp + kbase + 36);

#pragma unroll
    for (int i = 0; i < 16; ++i) {
        const bf16x8* q = Yb + ((size_t)(t0 + i) * 6) * 64 + lane;
        bf16x8 B0 = q[0], B1 = q[64], B2 = q[128], B3 = q[192], B4 = q[256], B5 = q[320];
        f32x4 xa = pa0, xb = pb0;
        pa0 = pa1; pb0 = pb1;
        if (i < 14) {
            pa1 = *(const f32x4*)(rowp + kbase + (i + 2) * 32);
            pb1 = *(const f32x4*)(rowp + kbase + (i + 2) * 32 + 4);
        }
        float xsv[8];
        *(f32x4*)(xsv) = xa; *(f32x4*)(xsv + 4) = xb;
        bf16x8 aX, aS, aSP;
#pragma unroll
        for (int jj = 0; jj < 8; ++jj) {
            float x  = xsv[jj];
            float ax = fabsf(x);
            float e  = __expf(-ax);
            float inv = __builtin_amdgcn_rcpf(1.f + e);
            float sig = (x >= 0.f) ? inv : e * inv;
            float sp  = fmaxf(x, 0.f) + __logf(1.f + e);
            aX[jj] = (__bf16)x; aS[jj] = (__bf16)sig; aSP[jj] = (__bf16)sp;
        }
        accX[0] = __builtin_amdgcn_mfma_f32_16x16x32_bf16(aX, B0, accX[0], 0, 0, 0);
        accS[0] = __builtin_amdgcn_mfma_f32_16x16x32_bf16(aS, B0, accS[0], 0, 0, 0);
        accX[1] = __builtin_amdgcn_mfma_f32_16x16x32_bf16(aX, B1, accX[1], 0, 0, 0);
        accS[1] = __builtin_amdgcn_mfma_f32_16x16x32_bf16(aS, B1, accS[1], 0, 0, 0);
        accX[2] = __builtin_amdgcn_mfma_f32_16x16x32_bf16(aX, B2, accX[2], 0, 0, 0);
        accS[2] = __builtin_amdgcn_mfma_f32_16x16x32_bf16(aS, B2, accS[2], 0, 0, 0);
        accX[3] = __builtin_amdgcn_mfma_f32_16x16x32_bf16(aX, B3, accX[3], 0, 0, 0);
        accS[3] = __builtin_amdgcn_mfma_f32_16x16x32_bf16(aS, B3, accS[3], 0, 0, 0);
        accX[4] = __builtin_amdgcn_mfma_f32_16x16x32_bf16(aX, B4, accX[4], 0, 0, 0);
        accS[4] = __builtin_amdgcn_mfma_f32_16x16x32_bf16(aS, B4, accS[4], 0, 0, 0);
        acc5S   = __builtin_amdgcn_mfma_f32_16x16x32_bf16(aS,  B5, acc5S, 0, 0, 0);
        acc5P   = __builtin_amdgcn_mfma_f32_16x16x32_bf16(aSP, B5, acc5P, 0, 0, 0);
    }

    // ---- epilogue pass 1: xy partials + row sums ----
#pragma unroll
    for (int j = 0; j < 5; ++j)
#pragma unroll
        for (int r = 0; r < 4; ++r) red[wave][j * 4 + r][lane] = accX[j][r];
    if (colL == 0) {
#pragma unroll
        for (int r = 0; r < 4; ++r) {
            rS[wave][quad * 4 + r]  = acc5S[r];
            rSP[wave][quad * 4 + r] = acc5P[r];
        }
    }
    __syncthreads();
#pragma unroll
    for (int v0 = 0; v0 < 5; ++v0) {
        int v = wave * 5 + v0;
        float s = red[0][v][lane] + red[1][v][lane] + red[2][v][lane] + red[3][v][lane];
        int j = v >> 2, r = v & 3;
        int n = n0 + quad * 4 + r, m = 16 * j + colL;   // verified C/D layout
        xypart[(size_t)ch * NM + n * M_ROWS + m] = s;
    }
    if (tid < 16) {
        rowS[ch * N_ROWS + n0 + tid] = rS[0][tid] + rS[1][tid] + rS[2][tid] + rS[3][tid];
    } else if (tid < 32) {
        int l = tid - 16;
        rowSP[ch * N_ROWS + n0 + l] = rSP[0][l] + rSP[1][l] + rSP[2][l] + rSP[3][l];
    }
    __syncthreads();
    // ---- epilogue pass 2: sy partials ----
#pragma unroll
    for (int j = 0; j < 5; ++j)
#pragma unroll
        for (int r = 0; r < 4; ++r) red[wave][j * 4 + r][lane] = accS[j][r];
    __syncthreads();
#pragma unroll
    for (int v0 = 0; v0 < 5; ++v0) {
        int v = wave * 5 + v0;
        float s = red[0][v][lane] + red[1][v][lane] + red[2][v][lane] + red[3][v][lane];
        int j = v >> 2, r = v & 3;
        int n = n0 + quad * 4 + r, m = 16 * j + colL;
        sypart[(size_t)ch * NM + n * M_ROWS + m] = s;
    }
}

// --- combine: reduce partials + all cost terms ---
__global__ void combine_kernel(const float* __restrict__ logits,
                               const int* __restrict__ tgt_labels,
                               const float* __restrict__ rowmax,
                               const float* __restrict__ rowsum,
                               const float* __restrict__ rowS,
                               const float* __restrict__ rowSP,
                               const float* __restrict__ ypart,
                               const float* __restrict__ xypart,
                               const float* __restrict__ sypart,
                               float* __restrict__ out) {
    int idx = blockIdx.x * blockDim.x + threadIdx.x;
    if (idx >= NM) return;
    int n = idx / M_ROWS, m = idx % M_ROWS;
    float xy = 0.f, sy = 0.f, ssumv = 0.f, spsumv = 0.f, ysum = 0.f;
#pragma unroll 8
    for (int g = 0; g < KS; ++g) {
        xy += xypart[(size_t)g * NM + idx];
        sy += sypart[(size_t)g * NM + idx];
        ssumv  += rowS[g * N_ROWS + n];
        spsumv += rowSP[g * N_ROWS + n];
    }
#pragma unroll 16
    for (int g = 0; g < YTCH; ++g) ysum += ypart[g * M_ROWS + m];
    int tid = tgt_labels[m];
    tid = min(max(tid, 0), K_CLS - 1);
    float p = expf(logits[n * K_CLS + tid] - rowmax[n]) / rowsum[n];
    float cost_class = -p;
    float cost_mask = (spsumv - xy) * (1.0f / PN);
    float cost_dice = 1.f - (2.f * sy + 1.f) / (ssumv + ysum + 1.f);
    out[idx] = 2.f * cost_class + 5.f * cost_mask + 5.f * cost_dice;
}

extern "C" void kernel_launch(void* const* d_in, const int* in_sizes, int n_in,
                              void* d_out, int out_size, void* d_ws, size_t ws_size,
                              hipStream_t stream) {
    const float* pred_logits = (const float*)d_in[0];   // (4,100,134)
    const float* pred_masks  = (const float*)d_in[1];   // (4,100,256,256)
    const int*   tgt_labels  = (const int*)d_in[2];     // (80,)
    const float* tgt_masks   = (const float*)d_in[3];   // (80,256,256)
    const int*   point_idx   = (const int*)d_in[4];     // (12544,)
    float* out = (float*)d_out;                         // (4,100,80)

    char* ws = (char*)d_ws;
    size_t off = 0;
    auto carve = [&](size_t nbytes) {
        char* p = ws + off;
        off += (nbytes + 255) & ~(size_t)255;
        return p;
    };
    // all buffers fully overwritten every launch -> NO zero-init anywhere
    unsigned int* bitmap = (unsigned int*)carve(WORDS * 4);            // 8 KB
    bf16x8* Yb    = (bf16x8*)carve((size_t)WORDS * 6 * 64 * 16);       // 12.6 MB
    float* rowmax = (float*)carve(N_ROWS * 4);
    float* rowsum = (float*)carve(N_ROWS * 4);
    float* ypart  = (float*)carve((size_t)YTCH * M_ROWS * 4);          // 80 KB
    float* rowS   = (float*)carve((size_t)KS * N_ROWS * 4);
    float* rowSP  = (float*)carve((size_t)KS * N_ROWS * 4);
    float* xypart = (float*)carve((size_t)KS * NM * 4);                // 4.1 MB
    float* sypart = (float*)carve((size_t)KS * NM * 4);                // 4.1 MB
    (void)ws_size; (void)in_sizes; (void)n_in; (void)out_size;

    sort_softmax_kernel<<<26, 1024, 0, stream>>>(point_idx, bitmap,
                                                 pred_logits, rowmax, rowsum);
    buildY_kernel<<<6 * YTCH, 512, 0, stream>>>(tgt_masks, bitmap, Yb, ypart);
    gemm_full_kernel<<<NSUB * KS, 256, 0, stream>>>(
        pred_masks, Yb, xypart, sypart, rowS, rowSP);
    combine_kernel<<<(NM + 255) / 256, 256, 0, stream>>>(
        pred_logits, tgt_labels, rowmax, rowsum, rowS, rowSP, ypart,
        xypart, sypart, out);
}

// Round 5
// 219.521 us; speedup vs baseline: 1.0480x; 1.0121x over previous
//
#include <hip/hip_runtime.h>
#include <math.h>

#define N_ROWS 400      // bs*Q
#define M_ROWS 80       // = 5*16
#define K_CLS  134
#define PN     12544
#define PFULL  65536    // 256*256
#define WORDS  (PFULL / 32)   // 2048 bitmap words == full-grid t-steps
#define NSUB   25       // 400/16 n-subtiles
#define KS     64       // k-chunks (full-grid split)
#define TCH    (WORDS / KS)   // 32 t-steps per chunk
#define ITERS  (TCH / 4)      // 8 t-steps per wave
#define NM     (N_ROWS * M_ROWS)
#define YTCH   256      // buildY t-chunks (8 t each)

typedef __attribute__((ext_vector_type(4))) float  f32x4;
typedef __attribute__((ext_vector_type(8))) __bf16 bf16x8;

__device__ __forceinline__ float wave_reduce_sum(float v) {
#pragma unroll
    for (int off = 32; off > 0; off >>= 1) v += __shfl_down(v, off, 64);
    return v;
}

// --- block 0: build selection bitmap. blocks 1..25: softmax stats. ---
__global__ __launch_bounds__(1024) void sort_softmax_kernel(
        const int* __restrict__ point_idx,
        unsigned int* __restrict__ bitmap_g,
        const float* __restrict__ pred_logits,
        float* __restrict__ rowmax, float* __restrict__ rowsum) {
    int tid = threadIdx.x;
    if (blockIdx.x == 0) {
        __shared__ unsigned int bits[WORDS];   // 8 KB
        bits[tid] = 0u; bits[tid + 1024] = 0u;
        __syncthreads();
        for (int i = tid; i < PN; i += 1024) {
            int p = point_idx[i];
            atomicOr(&bits[p >> 5], 1u << (p & 31));
        }
        __syncthreads();
        bitmap_g[tid]        = bits[tid];
        bitmap_g[tid + 1024] = bits[tid + 1024];
    } else {
        int wave = tid >> 6, lane = tid & 63;
        int n = (blockIdx.x - 1) * 16 + wave;       // < 400
        const float* row = pred_logits + n * K_CLS;
        float mx = -1e30f;
        for (int k = lane; k < K_CLS; k += 64) mx = fmaxf(mx, row[k]);
#pragma unroll
        for (int off = 32; off > 0; off >>= 1) mx = fmaxf(mx, __shfl_down(mx, off, 64));
        mx = __shfl(mx, 0, 64);
        float se = 0.f;
        for (int k = lane; k < K_CLS; k += 64) se += expf(row[k] - mx);
        se = wave_reduce_sum(se);
        if (lane == 0) { rowmax[n] = mx; rowsum[n] = se; }
    }
}

// --- build Y' directly as bf16 MFMA B-fragments, plus sel-fragment (slot 5)
//     and ypart partials. Frag (t,j): lane l holds B[k=t*32+(l>>4)*8+jj][m=16j+(l&15)].
//     Slot 5 column 0 = sel bits (enables MFMA row-sums in the GEMM). ---
__global__ __launch_bounds__(512) void buildY_kernel(
        const float* __restrict__ tgt_masks,
        const unsigned int* __restrict__ bitmap_g,
        bf16x8* __restrict__ Yb, float* __restrict__ ypart) {
    __shared__ float smem[128];
    int b = blockIdx.x;
    int j = b >> 8, tch = b & 255;
    int wave = threadIdx.x >> 6, lane = threadIdx.x & 63;
    int colL = lane & 15, quad = lane >> 4;
    int t = tch * 8 + wave;
    unsigned int w = bitmap_g[t];
    bf16x8 v;
    if (j < 5) {
        int m = 16 * j + colL;
        const float* yrow = tgt_masks + (size_t)m * PFULL + t * 32 + quad * 8;
        f32x4 ya = *(const f32x4*)(yrow);
        f32x4 yc = *(const f32x4*)(yrow + 4);
        float acc = 0.f;
#pragma unroll
        for (int jj = 0; jj < 4; ++jj) {
            float va = ((w >> (quad * 8 + jj)) & 1u)     ? (ya[jj] > 0.5f ? 1.f : 0.f) : 0.f;
            float vc = ((w >> (quad * 8 + jj + 4)) & 1u) ? (yc[jj] > 0.5f ? 1.f : 0.f) : 0.f;
            v[jj] = (__bf16)va; v[jj + 4] = (__bf16)vc;
            acc += va + vc;
        }
        Yb[((size_t)t * 6 + j) * 64 + lane] = v;
        acc += __shfl_down(acc, 32, 64);
        acc += __shfl_down(acc, 16, 64);
        if (quad == 0) smem[wave * 16 + colL] = acc;
        __syncthreads();
        if (threadIdx.x < 16) {
            float s = 0.f;
#pragma unroll
            for (int wv = 0; wv < 8; ++wv) s += smem[wv * 16 + threadIdx.x];
            ypart[tch * M_ROWS + 16 * j + threadIdx.x] = s;
        }
    } else {
        // sel fragment: column 0 only
#pragma unroll
        for (int jj = 0; jj < 8; ++jj) {
            float sv = (colL == 0 && ((w >> (quad * 8 + jj)) & 1u)) ? 1.f : 0.f;
            v[jj] = (__bf16)sv;
        }
        Yb[((size_t)t * 6 + 5) * 64 + lane] = v;
    }
}

// --- full-grid fused GEMM, software-pipelined:
//     A (HBM) prefetched 3 iters ahead; B fragments (L2/L3) register
//     double-buffered (load i+1 while computing i). 4 waves/SIMD pinned via
//     launch_bounds. Masked row-sums via sel fragment (slot 5). ---
__global__ __launch_bounds__(256, 4) void gemm_full_kernel(
        const float* __restrict__ pred_masks,
        const bf16x8* __restrict__ Yb,
        float* __restrict__ xypart, float* __restrict__ sypart,
        float* __restrict__ rowS, float* __restrict__ rowSP) {
    __shared__ float red[4][20][64];       // 20 KB
    __shared__ float rS[4][16], rSP[4][16];
    int tid = threadIdx.x;
    int wave = tid >> 6, lane = tid & 63;
    int colL = lane & 15, quad = lane >> 4;
    int nsub = blockIdx.x % NSUB, ch = blockIdx.x / NSUB;  // nsub fastest:
    int n0 = nsub * 16;                                    // consecutive blocks
    int t0 = ch * TCH + wave * ITERS;                      // share the Yb slice
    const float* rowp = pred_masks + (size_t)(n0 + colL) * PFULL;
    int kbase = t0 * 32 + quad * 8;

    f32x4 accX[5], accS[5];
    f32x4 zero = {0.f, 0.f, 0.f, 0.f};
#pragma unroll
    for (int j = 0; j < 5; ++j) { accX[j] = zero; accS[j] = zero; }
    f32x4 acc5S = zero, acc5P = zero;

    // A prefetch: depth 3
    f32x4 PA[3], PB[3];
#pragma unroll
    for (int d = 0; d < 3; ++d) {
        PA[d] = *(const f32x4*)(rowp + kbase + d * 32);
        PB[d] = *(const f32x4*)(rowp + kbase + d * 32 + 4);
    }
    // B prefetch: current buffer
    bf16x8 Bc[6], Bn[6];
    {
        const bf16x8* q = Yb + ((size_t)t0 * 6) * 64 + lane;
#pragma unroll
        for (int j = 0; j < 6; ++j) Bc[j] = q[j * 64];
    }

#pragma unroll
    for (int i = 0; i < ITERS; ++i) {
        // issue next-iteration B loads first (consumed next iter)
        if (i + 1 < ITERS) {
            const bf16x8* q = Yb + ((size_t)(t0 + i + 1) * 6) * 64 + lane;
#pragma unroll
            for (int j = 0; j < 6; ++j) Bn[j] = q[j * 64];
        }
        f32x4 xa = PA[0], xb = PB[0];
        PA[0] = PA[1]; PB[0] = PB[1];
        PA[1] = PA[2]; PB[1] = PB[2];
        if (i + 3 < ITERS) {
            PA[2] = *(const f32x4*)(rowp + kbase + (i + 3) * 32);
            PB[2] = *(const f32x4*)(rowp + kbase + (i + 3) * 32 + 4);
        }
        float xsv[8];
        *(f32x4*)(xsv) = xa; *(f32x4*)(xsv + 4) = xb;
        bf16x8 aX, aS, aSP;
#pragma unroll
        for (int jj = 0; jj < 8; ++jj) {
            float x  = xsv[jj];
            float ax = fabsf(x);
            float e  = __expf(-ax);
            float den = 1.f + e;
            float inv = __builtin_amdgcn_rcpf(den);
            float sig = (x >= 0.f) ? inv : e * inv;
            float sp  = fmaxf(x, 0.f) + __logf(den);
            aX[jj] = (__bf16)x; aS[jj] = (__bf16)sig; aSP[jj] = (__bf16)sp;
        }
        accX[0] = __builtin_amdgcn_mfma_f32_16x16x32_bf16(aX, Bc[0], accX[0], 0, 0, 0);
        accS[0] = __builtin_amdgcn_mfma_f32_16x16x32_bf16(aS, Bc[0], accS[0], 0, 0, 0);
        accX[1] = __builtin_amdgcn_mfma_f32_16x16x32_bf16(aX, Bc[1], accX[1], 0, 0, 0);
        accS[1] = __builtin_amdgcn_mfma_f32_16x16x32_bf16(aS, Bc[1], accS[1], 0, 0, 0);
        accX[2] = __builtin_amdgcn_mfma_f32_16x16x32_bf16(aX, Bc[2], accX[2], 0, 0, 0);
        accS[2] = __builtin_amdgcn_mfma_f32_16x16x32_bf16(aS, Bc[2], accS[2], 0, 0, 0);
        accX[3] = __builtin_amdgcn_mfma_f32_16x16x32_bf16(aX, Bc[3], accX[3], 0, 0, 0);
        accS[3] = __builtin_amdgcn_mfma_f32_16x16x32_bf16(aS, Bc[3], accS[3], 0, 0, 0);
        accX[4] = __builtin_amdgcn_mfma_f32_16x16x32_bf16(aX, Bc[4], accX[4], 0, 0, 0);
        accS[4] = __builtin_amdgcn_mfma_f32_16x16x32_bf16(aS, Bc[4], accS[4], 0, 0, 0);
        acc5S   = __builtin_amdgcn_mfma_f32_16x16x32_bf16(aS,  Bc[5], acc5S, 0, 0, 0);
        acc5P   = __builtin_amdgcn_mfma_f32_16x16x32_bf16(aSP, Bc[5], acc5P, 0, 0, 0);
#pragma unroll
        for (int j = 0; j < 6; ++j) Bc[j] = Bn[j];
    }

    // ---- epilogue pass 1: xy partials + row sums ----
#pragma unroll
    for (int j = 0; j < 5; ++j)
#pragma unroll
        for (int r = 0; r < 4; ++r) red[wave][j * 4 + r][lane] = accX[j][r];
    if (colL == 0) {
#pragma unroll
        for (int r = 0; r < 4; ++r) {
            rS[wave][quad * 4 + r]  = acc5S[r];
            rSP[wave][quad * 4 + r] = acc5P[r];
        }
    }
    __syncthreads();
#pragma unroll
    for (int v0 = 0; v0 < 5; ++v0) {
        int v = wave * 5 + v0;
        float s = red[0][v][lane] + red[1][v][lane] + red[2][v][lane] + red[3][v][lane];
        int j = v >> 2, r = v & 3;
        int n = n0 + quad * 4 + r, m = 16 * j + colL;   // verified C/D layout
        xypart[(size_t)ch * NM + n * M_ROWS + m] = s;
    }
    if (tid < 16) {
        rowS[ch * N_ROWS + n0 + tid] = rS[0][tid] + rS[1][tid] + rS[2][tid] + rS[3][tid];
    } else if (tid < 32) {
        int l = tid - 16;
        rowSP[ch * N_ROWS + n0 + l] = rSP[0][l] + rSP[1][l] + rSP[2][l] + rSP[3][l];
    }
    __syncthreads();
    // ---- epilogue pass 2: sy partials ----
#pragma unroll
    for (int j = 0; j < 5; ++j)
#pragma unroll
        for (int r = 0; r < 4; ++r) red[wave][j * 4 + r][lane] = accS[j][r];
    __syncthreads();
#pragma unroll
    for (int v0 = 0; v0 < 5; ++v0) {
        int v = wave * 5 + v0;
        float s = red[0][v][lane] + red[1][v][lane] + red[2][v][lane] + red[3][v][lane];
        int j = v >> 2, r = v & 3;
        int n = n0 + quad * 4 + r, m = 16 * j + colL;
        sypart[(size_t)ch * NM + n * M_ROWS + m] = s;
    }
}

// --- combine: reduce partials + all cost terms ---
__global__ void combine_kernel(const float* __restrict__ logits,
                               const int* __restrict__ tgt_labels,
                               const float* __restrict__ rowmax,
                               const float* __restrict__ rowsum,
                               const float* __restrict__ rowS,
                               const float* __restrict__ rowSP,
                               const float* __restrict__ ypart,
                               const float* __restrict__ xypart,
                               const float* __restrict__ sypart,
                               float* __restrict__ out) {
    int idx = blockIdx.x * blockDim.x + threadIdx.x;
    if (idx >= NM) return;
    int n = idx / M_ROWS, m = idx % M_ROWS;
    float xy = 0.f, sy = 0.f, ssumv = 0.f, spsumv = 0.f, ysum = 0.f;
#pragma unroll 8
    for (int g = 0; g < KS; ++g) {
        xy += xypart[(size_t)g * NM + idx];
        sy += sypart[(size_t)g * NM + idx];
        ssumv  += rowS[g * N_ROWS + n];
        spsumv += rowSP[g * N_ROWS + n];
    }
#pragma unroll 16
    for (int g = 0; g < YTCH; ++g) ysum += ypart[g * M_ROWS + m];
    int tid = tgt_labels[m];
    tid = min(max(tid, 0), K_CLS - 1);
    float p = expf(logits[n * K_CLS + tid] - rowmax[n]) / rowsum[n];
    float cost_class = -p;
    float cost_mask = (spsumv - xy) * (1.0f / PN);
    float cost_dice = 1.f - (2.f * sy + 1.f) / (ssumv + ysum + 1.f);
    out[idx] = 2.f * cost_class + 5.f * cost_mask + 5.f * cost_dice;
}

extern "C" void kernel_launch(void* const* d_in, const int* in_sizes, int n_in,
                              void* d_out, int out_size, void* d_ws, size_t ws_size,
                              hipStream_t stream) {
    const float* pred_logits = (const float*)d_in[0];   // (4,100,134)
    const float* pred_masks  = (const float*)d_in[1];   // (4,100,256,256)
    const int*   tgt_labels  = (const int*)d_in[2];     // (80,)
    const float* tgt_masks   = (const float*)d_in[3];   // (80,256,256)
    const int*   point_idx   = (const int*)d_in[4];     // (12544,)
    float* out = (float*)d_out;                         // (4,100,80)

    char* ws = (char*)d_ws;
    size_t off = 0;
    auto carve = [&](size_t nbytes) {
        char* p = ws + off;
        off += (nbytes + 255) & ~(size_t)255;
        return p;
    };
    // all buffers fully overwritten every launch -> NO zero-init anywhere
    unsigned int* bitmap = (unsigned int*)carve(WORDS * 4);            // 8 KB
    bf16x8* Yb    = (bf16x8*)carve((size_t)WORDS * 6 * 64 * 16);       // 12.6 MB
    float* rowmax = (float*)carve(N_ROWS * 4);
    float* rowsum = (float*)carve(N_ROWS * 4);
    float* ypart  = (float*)carve((size_t)YTCH * M_ROWS * 4);          // 80 KB
    float* rowS   = (float*)carve((size_t)KS * N_ROWS * 4);
    float* rowSP  = (float*)carve((size_t)KS * N_ROWS * 4);
    float* xypart = (float*)carve((size_t)KS * NM * 4);                // 8.2 MB
    float* sypart = (float*)carve((size_t)KS * NM * 4);                // 8.2 MB
    (void)ws_size; (void)in_sizes; (void)n_in; (void)out_size;

    sort_softmax_kernel<<<26, 1024, 0, stream>>>(point_idx, bitmap,
                                                 pred_logits, rowmax, rowsum);
    buildY_kernel<<<6 * YTCH, 512, 0, stream>>>(tgt_masks, bitmap, Yb, ypart);
    gemm_full_kernel<<<NSUB * KS, 256, 0, stream>>>(
        pred_masks, Yb, xypart, sypart, rowS, rowSP);
    combine_kernel<<<(NM + 255) / 256, 256, 0, stream>>>(
        pred_logits, tgt_labels, rowmax, rowsum, rowS, rowSP, ypart,
        xypart, sypart, out);
}